// Round 1
// baseline (645.913 us; speedup 1.0000x reference)
//
#include <hip/hip_runtime.h>
#include <math.h>

#define HW 9216
#define WD 96
#define NC 128

__device__ __forceinline__ int rfl(int v){ return __builtin_amdgcn_readfirstlane(v); }

// ---------------- K0: weight transposes ----------------
// wt_pw[c][o] = pw_w[o][c]
// off_wt[c][tap][j] = off_w[j][c][tap]
// wt_dc[k][c][o] = dc_w[o][c][k]
__global__ __launch_bounds__(256) void prep_weights(const float* __restrict__ pw_w,
    const float* __restrict__ off_w, const float* __restrict__ dc_w,
    float* __restrict__ wt_pw, float* __restrict__ off_wt, float* __restrict__ wt_dc){
  int t = blockIdx.x*256 + threadIdx.x;
  if (t < 16384){ int c = t>>7, o = t&127; wt_pw[c*128+o] = pw_w[o*128+c]; }
  if (t < 20736){ int c = t/162, r = t-162*(t/162); int tap = r/18, j = r-18*(r/18);
                  off_wt[t] = off_w[(j*128+c)*9+tap]; }
  if (t < 147456){ int k = t/16384, r2 = t&16383; int c = r2>>7, o = r2&127;
                   wt_dc[t] = dc_w[(o*128+c)*9+k]; }
}

// ---------------- K1: depthwise 3x3 + bias ----------------
__global__ __launch_bounds__(256) void dw_conv(const float* __restrict__ x,
    const float* __restrict__ w, const float* __restrict__ bias, float* __restrict__ h1){
  int n = blockIdx.x*256 + threadIdx.x;          // 4718592 total
  int bc = rfl(n / HW);                          // block-uniform (9216 % 256 == 0)
  int p = n - bc*HW;
  int c = bc & 127;
  int yy = p / WD, xx = p - (p/WD)*WD;
  const float* xc = x + (size_t)bc*HW;
  float acc = bias[c];
  #pragma unroll
  for (int r=0;r<3;r++){
    int y2 = yy + r - 1;
    #pragma unroll
    for (int cc2=0;cc2<3;cc2++){
      int x2 = xx + cc2 - 1;
      if (y2>=0 && y2<96 && x2>=0 && x2<96)
        acc = fmaf(w[c*9 + r*3 + cc2], xc[y2*WD + x2], acc);
    }
  }
  h1[n] = acc;
}

// ---------------- K2: pointwise 1x1 GEMM (lane=pixel, acc over 128 o, SGPR weights) ----
__global__ __launch_bounds__(128) void pw_gemm(const float* __restrict__ h1,
    const float* __restrict__ wt_pw, const float* __restrict__ pw_b, float* __restrict__ h2){
  int blk = blockIdx.x;                      // 576 = 4b * 144 ptiles
  int b = rfl(blk/144); int pbase = rfl(blk - (blk/144)*144)*64;
  int lane = threadIdx.x & 63; int wv = rfl(threadIdx.x >> 6);   // c-split over 2 waves
  int p = pbase + lane;
  const float* a = h1 + (size_t)(b*NC + wv*64)*HW + p;
  float acc[128];
  #pragma unroll
  for (int o=0;o<128;o++) acc[o]=0.f;
  for (int ci=0; ci<64; ci++){
    float av = a[(size_t)ci*HW];
    const float* wr = wt_pw + (wv*64+ci)*128;
    #pragma unroll
    for (int o=0;o<128;o++) acc[o] = fmaf(wr[o], av, acc[o]);
  }
  __shared__ float red[2][64][69];
  if (wv==0){
    #pragma unroll
    for (int i=0;i<64;i++) red[0][lane][i] = acc[64+i];
  } else {
    #pragma unroll
    for (int i=0;i<64;i++) red[1][lane][i] = acc[i];
  }
  __syncthreads();
  if (wv==0){
    #pragma unroll
    for (int i=0;i<64;i++){
      float v = acc[i] + red[1][lane][i] + pw_b[i];
      h2[(size_t)(b*NC + i)*HW + p] = v;
    }
  } else {
    #pragma unroll
    for (int i=0;i<64;i++){
      float v = acc[64+i] + red[0][lane][i] + pw_b[64+i];
      h2[(size_t)(b*NC + 64+i)*HW + p] = v;
    }
  }
}

// ---------------- K3: InstanceNorm stats ----------------
__global__ __launch_bounds__(256) void inorm_stats(const float* __restrict__ h2, float* __restrict__ st){
  int bc = blockIdx.x;                       // 512
  const float* src = h2 + (size_t)bc*HW;
  float s=0.f, ss=0.f;
  for (int i=threadIdx.x; i<HW; i+=256){ float v=src[i]; s+=v; ss=fmaf(v,v,ss); }
  #pragma unroll
  for (int off=32; off; off>>=1){ s += __shfl_down(s,off); ss += __shfl_down(ss,off); }
  __shared__ float rsm[2][4];
  int wave = threadIdx.x>>6, lane = threadIdx.x&63;
  if (lane==0){ rsm[0][wave]=s; rsm[1][wave]=ss; }
  __syncthreads();
  if (threadIdx.x==0){
    float S = rsm[0][0]+rsm[0][1]+rsm[0][2]+rsm[0][3];
    float SS= rsm[1][0]+rsm[1][1]+rsm[1][2]+rsm[1][3];
    float mu = S * (1.f/9216.f);
    float var = SS * (1.f/9216.f) - mu*mu;
    st[bc*2]   = mu;
    st[bc*2+1] = rsqrtf(var + 1e-5f);
  }
}

// ---------------- K4: dsc (NCHW) + dsc_t (NHWC) ----------------
__global__ __launch_bounds__(256) void make_dsc(const float* __restrict__ h2,
    const float* __restrict__ st, float* __restrict__ dsc, float* __restrict__ dsc_t){
  int blk = blockIdx.x;                      // 1152 = 4b * 2ch * 144pt
  int pt = blk % 144; int r = blk/144; int ch = r & 1; int b = r >> 1;
  int c0 = ch*64, pbase = pt*64;
  __shared__ float tile[64][65];
  int tr = threadIdx.x >> 2;                 // 0..63
  int g  = threadIdx.x & 3;                  // 0..3
  int c  = c0 + tr;
  float mu = st[(b*128+c)*2];
  float rs = st[(b*128+c)*2+1];
  const float* src = h2 + (size_t)(b*128+c)*HW + pbase + g*16;
  float* d = dsc + (size_t)(b*128+c)*HW + pbase + g*16;
  #pragma unroll
  for (int i=0;i<4;i++){
    float4 v = *(const float4*)(src + i*4);
    v.x=(v.x-mu)*rs; v.y=(v.y-mu)*rs; v.z=(v.z-mu)*rs; v.w=(v.w-mu)*rs;
    *(float4*)(d + i*4) = v;
    tile[tr][g*16+i*4+0]=v.x; tile[tr][g*16+i*4+1]=v.y;
    tile[tr][g*16+i*4+2]=v.z; tile[tr][g*16+i*4+3]=v.w;
  }
  __syncthreads();
  int pr = tr;
  float* dt = dsc_t + ((size_t)b*HW + pbase + pr)*NC + c0 + g*16;
  #pragma unroll
  for (int i=0;i<4;i++){
    float4 v;
    v.x = tile[g*16+i*4+0][pr];
    v.y = tile[g*16+i*4+1][pr];
    v.z = tile[g*16+i*4+2][pr];
    v.w = tile[g*16+i*4+3][pr];
    *(float4*)(dt + i*4) = v;
  }
}

// ---------------- K5: offset conv 3x3 (128 -> 18), c-split x4 partials ----------------
__global__ __launch_bounds__(256) void off_conv(const float* __restrict__ dsc,
    const float* __restrict__ owt, float* __restrict__ po){
  int blk = blockIdx.x;                      // 576 = 4b * 4q * 36 tiles
  int tx = blk % 6; int ty = (blk/6) % 6; int q = (blk/36) & 3; int b = blk/144;
  int x0 = tx*16, y0 = ty*16;
  int lx = threadIdx.x & 15, ly = threadIdx.x >> 4;
  __shared__ float tile[18][20];
  float acc[18];
  #pragma unroll
  for (int j=0;j<18;j++) acc[j]=0.f;
  const float* base = dsc + (size_t)(b*128 + q*32)*HW;
  #pragma unroll 1
  for (int c=0;c<32;c++){
    __syncthreads();
    for (int i=threadIdx.x; i<324; i+=256){
      int rr = i/18, cc = i-18*(i/18);
      int yy = y0-1+rr, xx2 = x0-1+cc;
      float v = 0.f;
      if (yy>=0 && yy<96 && xx2>=0 && xx2<96) v = base[(size_t)c*HW + yy*WD + xx2];
      tile[rr][cc] = v;
    }
    __syncthreads();
    const float* wt = owt + (q*32+c)*162;    // uniform -> s_load
    #pragma unroll
    for (int tap=0;tap<9;tap++){
      float v = tile[ly + tap/3][lx + tap%3];
      #pragma unroll
      for (int j=0;j<18;j++) acc[j] = fmaf(wt[tap*18+j], v, acc[j]);
    }
  }
  float* dst = po + (size_t)(q*4+b)*18*HW;
  int p = (y0+ly)*WD + x0+lx;
  #pragma unroll
  for (int j=0;j<18;j++) dst[(size_t)j*HW + p] = acc[j];
}

// ---------------- K6a: bilinear precompute (weights + clamped addresses) ----------------
__global__ __launch_bounds__(256) void precomp(const float* __restrict__ po,
    const float* __restrict__ off_b, float4* __restrict__ wg, ushort4* __restrict__ ad){
  int n = blockIdx.x*256 + threadIdx.x;      // 331776 = 4b * 9k * 9216
  int bk = rfl(n / HW);
  int p = n - bk*HW;
  int k = bk % 9; int b = bk / 9;
  int jy = 2*k, jx = jy+1;
  float dy = off_b[jy], dx = off_b[jx];
  #pragma unroll
  for (int q=0;q<4;q++){
    dy += po[((size_t)(q*4+b)*18 + jy)*HW + p];
    dx += po[((size_t)(q*4+b)*18 + jx)*HW + p];
  }
  float ys = (float)(p/WD + k/3 - 1) + dy;
  float xs = (float)(p%WD + k%3 - 1) + dx;
  float fy0 = floorf(ys), fx0 = floorf(xs);
  float wy = ys - fy0, wx = xs - fx0;
  int y0 = (int)fy0, x0 = (int)fx0;
  int y1 = y0+1, x1 = x0+1;
  float vy0 = (y0>=0 && y0<=95) ? 1.f : 0.f;
  float vy1 = (y1>=0 && y1<=95) ? 1.f : 0.f;
  float vx0 = (x0>=0 && x0<=95) ? 1.f : 0.f;
  float vx1 = (x1>=0 && x1<=95) ? 1.f : 0.f;
  int y0c=min(max(y0,0),95), y1c=min(max(y1,0),95);
  int x0c=min(max(x0,0),95), x1c=min(max(x1,0),95);
  float4 w4;
  w4.x = (1.f-wy)*(1.f-wx)*vy0*vx0;
  w4.y = (1.f-wy)*wx*vy0*vx1;
  w4.z = wy*(1.f-wx)*vy1*vx0;
  w4.w = wy*wx*vy1*vx1;
  wg[n] = w4;
  ad[n] = make_ushort4((unsigned short)(y0c*WD+x0c), (unsigned short)(y0c*WD+x1c),
                       (unsigned short)(y1c*WD+x0c), (unsigned short)(y1c*WD+x1c));
}

// ---------------- K6b: deformable conv GEMM (lane=pixel, acc[128] o, SGPR weights) ------
__global__ __launch_bounds__(256) void deform_gemm(const float* __restrict__ dsc_t,
    const float* __restrict__ wt_dc, const float* __restrict__ dc_b,
    const float4* __restrict__ wg, const ushort4* __restrict__ ad,
    float* __restrict__ dc_t){
  int blk = blockIdx.x;                      // 576 = 4b * 144 ptiles
  int b = rfl(blk/144); int pbase = rfl(blk - (blk/144)*144)*64;
  int lane = threadIdx.x & 63; int wv = rfl(threadIdx.x >> 6);   // c-split over 4 waves
  __shared__ float S[8448];                  // S[c][p]: rows of 66 (also reused as reduce scratch, rows of 33)
  float acc[128];
  #pragma unroll
  for (int o=0;o<128;o++) acc[o]=0.f;
  const float* dtb = dsc_t + (size_t)b*HW*NC;
  int cb = threadIdx.x & 127;
  int ph = threadIdx.x >> 7;
  #pragma unroll 1
  for (int k=0;k<9;k++){
    __syncthreads();
    int base = (b*9+k)*HW + pbase;
    #pragma unroll 4
    for (int pp=0; pp<32; pp++){
      int p2 = pp*2 + ph;
      float4 w = wg[base + p2];
      ushort4 a = ad[base + p2];
      float v = w.x*dtb[(int)a.x*NC + cb] + w.y*dtb[(int)a.y*NC + cb]
              + w.z*dtb[(int)a.z*NC + cb] + w.w*dtb[(int)a.w*NC + cb];
      S[cb*66 + p2] = v;
    }
    __syncthreads();
    const float* wk = wt_dc + k*16384 + wv*32*128;   // uniform -> s_load
    #pragma unroll 2
    for (int ci=0; ci<32; ci++){
      float sv = S[(wv*32+ci)*66 + lane];
      const float* wr = wk + ci*128;
      #pragma unroll
      for (int o=0;o<128;o++) acc[o] = fmaf(wr[o], sv, acc[o]);
    }
  }
  // cross-wave reduce (4 partial c-ranges) + bias + NHWC store, 4 o-chunks of 32
  #pragma unroll
  for (int oc=0; oc<4; oc++){
    __syncthreads();
    #pragma unroll
    for (int i=0;i<32;i++) S[threadIdx.x*33 + i] = acc[oc*32+i];
    __syncthreads();
    int o = threadIdx.x & 31; int pr = threadIdx.x >> 5;   // pr 0..7
    float bias = dc_b[oc*32 + o];
    #pragma unroll
    for (int i=0;i<8;i++){
      int p = pr + i*8;
      float v = S[p*33+o] + S[(64+p)*33+o] + S[(128+p)*33+o] + S[(192+p)*33+o] + bias;
      dc_t[((size_t)b*HW + pbase + p)*NC + oc*32 + o] = v;
    }
  }
}

// ---------------- K7: channel LayerNorm + sigmoid gate + multiply ----------------
__global__ __launch_bounds__(64) void epilogue(const float* __restrict__ dc_t,
    const float* __restrict__ dsc, const float* __restrict__ ln_g,
    const float* __restrict__ ln_b, float* __restrict__ out){
  int blk = blockIdx.x;                      // 576
  int b = rfl(blk/144);
  int p = (blk - (blk/144)*144)*64 + threadIdx.x;
  const float* row = dc_t + ((size_t)b*HW + p)*NC;
  float s=0.f, ss=0.f;
  #pragma unroll
  for (int c=0;c<128;c+=4){
    float4 v = *(const float4*)(row+c);
    s += v.x+v.y+v.z+v.w;
    ss += v.x*v.x+v.y*v.y+v.z*v.z+v.w*v.w;
  }
  float m = s*(1.f/128.f);
  float var = ss*(1.f/128.f) - m*m;
  float rs = rsqrtf(var + 1e-5f);
  #pragma unroll 4
  for (int c=0;c<128;c++){
    float ln = (row[c]-m)*rs*ln_g[c] + ln_b[c];
    float attn = 1.f/(1.f+__expf(-ln));
    size_t idx = (size_t)(b*NC+c)*HW + p;
    out[idx] = dsc[idx]*attn;
  }
}

extern "C" void kernel_launch(void* const* d_in, const int* in_sizes, int n_in,
                              void* d_out, int out_size, void* d_ws, size_t ws_size,
                              hipStream_t stream){
  const float* x    = (const float*)d_in[0];
  const float* dw_w = (const float*)d_in[1];
  const float* dw_b = (const float*)d_in[2];
  const float* pw_w = (const float*)d_in[3];
  const float* pw_b = (const float*)d_in[4];
  const float* off_w= (const float*)d_in[5];
  const float* off_b= (const float*)d_in[6];
  const float* dc_w = (const float*)d_in[7];
  const float* dc_b = (const float*)d_in[8];
  const float* ln_g = (const float*)d_in[9];
  const float* ln_b = (const float*)d_in[10];
  float* out = (float*)d_out;

  float* W    = (float*)d_ws;
  float* bufA = W;                      // h1, later dsc (NCHW)
  float* bufB = W + 4718592;            // h2, later dc_t (NHWC)
  float* bufT = W + 9437184;            // dsc_t (NHWC)
  float* po   = W + 14155776;           // 4 partial offset-conv buffers [q][b][18][HW]
  float4*  wg = (float4*)(W + 16809984);
  ushort4* ad = (ushort4*)(W + 18137088);
  float* st   = W + 18800640;
  float* wpw  = W + 18801664;
  float* owt  = W + 18818048;
  float* wdc  = W + 18838784;           // end: 18986240 floats (~76 MB)

  prep_weights<<<576, 256, 0, stream>>>(pw_w, off_w, dc_w, wpw, owt, wdc);
  dw_conv     <<<18432, 256, 0, stream>>>(x, dw_w, dw_b, bufA);
  pw_gemm     <<<576, 128, 0, stream>>>(bufA, wpw, pw_b, bufB);
  inorm_stats <<<512, 256, 0, stream>>>(bufB, st);
  make_dsc    <<<1152, 256, 0, stream>>>(bufB, st, bufA, bufT);
  off_conv    <<<576, 256, 0, stream>>>(bufA, owt, po);
  precomp     <<<1296, 256, 0, stream>>>(po, off_b, wg, ad);
  deform_gemm <<<576, 256, 0, stream>>>(bufT, wdc, dc_b, wg, ad, bufB);
  epilogue    <<<576, 64, 0, stream>>>(bufB, bufA, ln_g, ln_b, out);
}

// Round 2
// 336.964 us; speedup vs baseline: 1.9169x; 1.9169x over previous
//
#include <hip/hip_runtime.h>
#include <math.h>

#define HW 9216
#define WD 96
#define NC 128

typedef unsigned short u16;
typedef __attribute__((ext_vector_type(8))) short short8;
typedef __attribute__((ext_vector_type(4))) float v4f;

__device__ __forceinline__ int rfl(int v){ return __builtin_amdgcn_readfirstlane(v); }
__device__ __forceinline__ float bu2f(u16 s){ return __uint_as_float(((unsigned)s)<<16); }
__device__ __forceinline__ u16 f2b(float f){ unsigned u = __float_as_uint(f);
  return (u16)((u + 0x7fffu + ((u>>16)&1u))>>16); }

// ---------------- K0: weight prep ----------------
// wpwb[o][c] = bf16(pw_w[o][c])
// off_wt[c][tap][j] = off_w[j][c][tap]            (fp32)
// wdcb[o][k*128+c] = bf16(dc_w[o][c][k])          (Wt rows = o, K = tap*128+c)
__global__ __launch_bounds__(256) void prep_weights(const float* __restrict__ pw_w,
    const float* __restrict__ off_w, const float* __restrict__ dc_w,
    u16* __restrict__ wpwb, float* __restrict__ off_wt, u16* __restrict__ wdcb){
  int t = blockIdx.x*256 + threadIdx.x;
  if (t < 16384) wpwb[t] = f2b(pw_w[t]);
  if (t < 20736){ int c = t/162, r = t-162*(t/162); int tap = r/18, j = r-18*tap;
                  off_wt[t] = off_w[(j*128+c)*9+tap]; }
  if (t < 147456){ int o = t/1152, r = t - o*1152; int k = r>>7, c = r&127;
                   wdcb[t] = f2b(dc_w[(o*128+c)*9 + k]); }
}

// ---------------- K1: depthwise 3x3 + bias (NCHW fp32) ----------------
__global__ __launch_bounds__(256) void dw_conv(const float* __restrict__ x,
    const float* __restrict__ w, const float* __restrict__ bias, float* __restrict__ h1){
  int n = blockIdx.x*256 + threadIdx.x;          // 4718592 total
  int bc = rfl(n / HW);
  int p = n - bc*HW;
  int c = bc & 127;
  int yy = p / WD, xx = p - (p/WD)*WD;
  const float* xc = x + (size_t)bc*HW;
  float acc = bias[c];
  #pragma unroll
  for (int r=0;r<3;r++){
    int y2 = yy + r - 1;
    #pragma unroll
    for (int cc2=0;cc2<3;cc2++){
      int x2 = xx + cc2 - 1;
      if (y2>=0 && y2<96 && x2>=0 && x2<96)
        acc = fmaf(w[c*9 + r*3 + cc2], xc[y2*WD + x2], acc);
    }
  }
  h1[n] = acc;
}

// ---------------- K2: pointwise 1x1 via MFMA  (A=weights[o][c], B=act[c][px]) ----
__global__ __launch_bounds__(256) void pw_mfma(const float* __restrict__ h1,
    const u16* __restrict__ wpwb, const float* __restrict__ pw_b, float* __restrict__ h2){
  __shared__ short Aw[128*136];
  __shared__ short Bw[128*68];
  int blk = blockIdx.x; int row0 = blk*64;       // 576 blocks
  int b = rfl(row0/HW); int pbase = rfl(row0 - b*HW);
  int t = threadIdx.x;
  #pragma unroll
  for (int i=0;i<8;i++){                          // stage full W (128x128 bf16)
    int idx = i*256 + t; int o = idx>>4, seg = idx&15;
    *(short8*)&Aw[o*136 + seg*8] = *(const short8*)(wpwb + o*128 + seg*8);
  }
  #pragma unroll
  for (int i=0;i<8;i++){                          // stage act tile [128c][64px] fp32->bf16
    int idx = i*256 + t; int c = idx>>4, seg = idx&15;
    float4 v = *(const float4*)(h1 + (size_t)(b*NC+c)*HW + pbase + seg*4);
    ushort4 pk = make_ushort4(f2b(v.x), f2b(v.y), f2b(v.z), f2b(v.w));
    *(ushort4*)&Bw[c*68 + seg*4] = pk;
  }
  __syncthreads();
  int w = rfl(t>>6); int l = t&63; int q = l>>4; int ln = l&15;
  v4f acc[8];
  #pragma unroll
  for (int mt=0;mt<8;mt++) acc[mt] = (v4f){0.f,0.f,0.f,0.f};
  #pragma unroll
  for (int ks=0;ks<4;ks++){
    short8 bf;
    #pragma unroll
    for (int j=0;j<8;j++) bf[j] = Bw[(ks*32 + q*8 + j)*68 + w*16 + ln];
    #pragma unroll
    for (int mt=0;mt<8;mt++){
      short8 af = *(short8*)&Aw[(mt*16+ln)*136 + ks*32 + q*8];
      acc[mt] = __builtin_amdgcn_mfma_f32_16x16x32_bf16(af, bf, acc[mt], 0,0,0);
    }
  }
  int px = pbase + w*16 + ln;
  #pragma unroll
  for (int mt=0;mt<8;mt++){
    #pragma unroll
    for (int r=0;r<4;r++){
      int o = mt*16 + q*4 + r;
      h2[(size_t)(b*NC+o)*HW + px] = acc[mt][r] + pw_b[o];
    }
  }
}

// ---------------- K3: InstanceNorm stats ----------------
__global__ __launch_bounds__(256) void inorm_stats(const float* __restrict__ h2, float* __restrict__ st){
  int bc = blockIdx.x;                       // 512
  const float* src = h2 + (size_t)bc*HW;
  float s=0.f, ss=0.f;
  for (int i=threadIdx.x; i<HW; i+=256){ float v=src[i]; s+=v; ss=fmaf(v,v,ss); }
  #pragma unroll
  for (int off=32; off; off>>=1){ s += __shfl_down(s,off); ss += __shfl_down(ss,off); }
  __shared__ float rsm[2][4];
  int wave = threadIdx.x>>6, lane = threadIdx.x&63;
  if (lane==0){ rsm[0][wave]=s; rsm[1][wave]=ss; }
  __syncthreads();
  if (threadIdx.x==0){
    float S = rsm[0][0]+rsm[0][1]+rsm[0][2]+rsm[0][3];
    float SS= rsm[1][0]+rsm[1][1]+rsm[1][2]+rsm[1][3];
    float mu = S * (1.f/9216.f);
    float var = SS * (1.f/9216.f) - mu*mu;
    st[bc*2]   = mu;
    st[bc*2+1] = rsqrtf(var + 1e-5f);
  }
}

// ---------------- K4: dsc (NCHW fp32) + dscT (NHWC bf16) ----------------
__global__ __launch_bounds__(256) void make_dsc(const float* __restrict__ h2,
    const float* __restrict__ st, float* __restrict__ dsc, u16* __restrict__ dscT){
  int blk = blockIdx.x;                      // 1152 = 4b * 2ch * 144pt
  int pt = blk % 144; int r = blk/144; int ch = r & 1; int b = r >> 1;
  int c0 = ch*64, pbase = pt*64;
  __shared__ float tile[64][65];
  int tr = threadIdx.x >> 2;                 // 0..63
  int g  = threadIdx.x & 3;                  // 0..3
  int c  = c0 + tr;
  float mu = st[(b*128+c)*2];
  float rs = st[(b*128+c)*2+1];
  const float* src = h2 + (size_t)(b*128+c)*HW + pbase + g*16;
  float* d = dsc + (size_t)(b*128+c)*HW + pbase + g*16;
  #pragma unroll
  for (int i=0;i<4;i++){
    float4 v = *(const float4*)(src + i*4);
    v.x=(v.x-mu)*rs; v.y=(v.y-mu)*rs; v.z=(v.z-mu)*rs; v.w=(v.w-mu)*rs;
    *(float4*)(d + i*4) = v;
    tile[tr][g*16+i*4+0]=v.x; tile[tr][g*16+i*4+1]=v.y;
    tile[tr][g*16+i*4+2]=v.z; tile[tr][g*16+i*4+3]=v.w;
  }
  __syncthreads();
  int pr = tr;
  u16* dt = dscT + ((size_t)b*HW + pbase + pr)*NC + c0 + g*16;
  #pragma unroll
  for (int i=0;i<4;i++){
    ushort4 pk = make_ushort4(f2b(tile[g*16+i*4+0][pr]), f2b(tile[g*16+i*4+1][pr]),
                              f2b(tile[g*16+i*4+2][pr]), f2b(tile[g*16+i*4+3][pr]));
    *(ushort4*)(dt + i*4) = pk;
  }
}

// ---------------- K5: offset conv 3x3 (128 -> 18), c-split x4 partials ----------------
__global__ __launch_bounds__(256) void off_conv(const float* __restrict__ dsc,
    const float* __restrict__ owt, float* __restrict__ po){
  int blk = blockIdx.x;                      // 576 = 4b * 4q * 36 tiles
  int tx = blk % 6; int ty = (blk/6) % 6; int q = (blk/36) & 3; int b = blk/144;
  int x0 = tx*16, y0 = ty*16;
  int lx = threadIdx.x & 15, ly = threadIdx.x >> 4;
  __shared__ float tile[18][20];
  float acc[18];
  #pragma unroll
  for (int j=0;j<18;j++) acc[j]=0.f;
  const float* base = dsc + (size_t)(b*128 + q*32)*HW;
  #pragma unroll 1
  for (int c=0;c<32;c++){
    __syncthreads();
    for (int i=threadIdx.x; i<324; i+=256){
      int rr = i/18, cc = i-18*(i/18);
      int yy = y0-1+rr, xx2 = x0-1+cc;
      float v = 0.f;
      if (yy>=0 && yy<96 && xx2>=0 && xx2<96) v = base[(size_t)c*HW + yy*WD + xx2];
      tile[rr][cc] = v;
    }
    __syncthreads();
    const float* wt = owt + (q*32+c)*162;
    #pragma unroll
    for (int tap=0;tap<9;tap++){
      float v = tile[ly + tap/3][lx + tap%3];
      #pragma unroll
      for (int j=0;j<18;j++) acc[j] = fmaf(wt[tap*18+j], v, acc[j]);
    }
  }
  float* dst = po + (size_t)(q*4+b)*18*HW;
  int p = (y0+ly)*WD + x0+lx;
  #pragma unroll
  for (int j=0;j<18;j++) dst[(size_t)j*HW + p] = acc[j];
}

// ---------------- K6a: bilinear precompute (weights + clamped addresses) ----------------
__global__ __launch_bounds__(256) void precomp(const float* __restrict__ po,
    const float* __restrict__ off_b, float4* __restrict__ wg, ushort4* __restrict__ ad){
  int n = blockIdx.x*256 + threadIdx.x;      // 331776 = 4b * 9k * 9216
  int bk = rfl(n / HW);
  int p = n - bk*HW;
  int k = bk % 9; int b = bk / 9;
  int jy = 2*k, jx = jy+1;
  float dy = off_b[jy], dx = off_b[jx];
  #pragma unroll
  for (int q=0;q<4;q++){
    dy += po[((size_t)(q*4+b)*18 + jy)*HW + p];
    dx += po[((size_t)(q*4+b)*18 + jx)*HW + p];
  }
  float ys = (float)(p/WD + k/3 - 1) + dy;
  float xs = (float)(p%WD + k%3 - 1) + dx;
  float fy0 = floorf(ys), fx0 = floorf(xs);
  float wy = ys - fy0, wx = xs - fx0;
  int y0 = (int)fy0, x0 = (int)fx0;
  int y1 = y0+1, x1 = x0+1;
  float vy0 = (y0>=0 && y0<=95) ? 1.f : 0.f;
  float vy1 = (y1>=0 && y1<=95) ? 1.f : 0.f;
  float vx0 = (x0>=0 && x0<=95) ? 1.f : 0.f;
  float vx1 = (x1>=0 && x1<=95) ? 1.f : 0.f;
  int y0c=min(max(y0,0),95), y1c=min(max(y1,0),95);
  int x0c=min(max(x0,0),95), x1c=min(max(x1,0),95);
  float4 w4;
  w4.x = (1.f-wy)*(1.f-wx)*vy0*vx0;
  w4.y = (1.f-wy)*wx*vy0*vx1;
  w4.z = wy*(1.f-wx)*vy1*vx0;
  w4.w = wy*wx*vy1*vx1;
  wg[n] = w4;
  ad[n] = make_ushort4((u16)(y0c*WD+x0c), (u16)(y0c*WD+x1c),
                       (u16)(y1c*WD+x0c), (u16)(y1c*WD+x1c));
}

// ---------------- K6b: fused deform conv: gather->LDS + MFMA GEMM ----------------
// C[px 64][o 128] = sum over K=1152 (k*128+c) of sampled[px][k,c] * Wt[o][k*128+c]
__global__ __launch_bounds__(256) void deform_mfma(const u16* __restrict__ dscT,
    const u16* __restrict__ wdcb, const float* __restrict__ dc_b,
    const float4* __restrict__ wg, const ushort4* __restrict__ ad,
    float* __restrict__ dc_t){
  __shared__ short As[64*40];                // sampled A-tile, stride 40 (pad)
  __shared__ short Bs[128*40];               // Wt tile (B^T rows = o), stride 40
  int blk = blockIdx.x; int row0 = blk*64;   // 576 blocks
  int b = rfl(row0/HW); int pbase = rfl(row0 - b*HW);
  int t = threadIdx.x;
  int am = t>>2, aseg = t&3;                 // A staging: pixel, 8-ch group
  int o0 = t>>2, bseg = t&3;                 // B staging: o row, 8-k group
  int w = rfl(t>>6); int l = t&63; int q = l>>4; int ln = l&15;
  const u16* db0 = dscT + (size_t)b*HW*NC;
  float4 wv; ushort4 av; uint4 r0,r1,r2,r3, wb0, wb1;
  auto prefetch = [&](int s){
    int k = s>>2; int cs = ((s&3)<<5) + aseg*8;
    int wgi = (b*9 + k)*HW + pbase + am;
    wv = wg[wgi]; av = ad[wgi];
    const u16* db = db0 + cs;
    r0 = *(const uint4*)(db + (int)av.x*NC);
    r1 = *(const uint4*)(db + (int)av.y*NC);
    r2 = *(const uint4*)(db + (int)av.z*NC);
    r3 = *(const uint4*)(db + (int)av.w*NC);
    const u16* wp = wdcb + s*32 + bseg*8;
    wb0 = *(const uint4*)(wp + o0*1152);
    wb1 = *(const uint4*)(wp + (o0+64)*1152);
  };
  auto commit = [&](){
    const u16* pa=(const u16*)&r0; const u16* pb=(const u16*)&r1;
    const u16* pc=(const u16*)&r2; const u16* pd=(const u16*)&r3;
    short8 sv;
    #pragma unroll
    for (int j=0;j<8;j++){
      float f = wv.x*bu2f(pa[j]) + wv.y*bu2f(pb[j]) + wv.z*bu2f(pc[j]) + wv.w*bu2f(pd[j]);
      sv[j] = (short)f2b(f);
    }
    *(short8*)&As[am*40 + aseg*8] = sv;
    *(short8*)&Bs[o0*40 + bseg*8] = *(short8*)&wb0;
    *(short8*)&Bs[(o0+64)*40 + bseg*8] = *(short8*)&wb1;
  };
  v4f acc[8];
  #pragma unroll
  for (int nt=0;nt<8;nt++) acc[nt] = (v4f){0.f,0.f,0.f,0.f};
  prefetch(0); commit();
  __syncthreads();
  #pragma unroll 1
  for (int s=0;s<36;s++){
    if (s<35) prefetch(s+1);
    short8 af = *(short8*)&As[(w*16+ln)*40 + q*8];
    #pragma unroll
    for (int nt=0;nt<8;nt++){
      short8 bf = *(short8*)&Bs[(nt*16+ln)*40 + q*8];
      acc[nt] = __builtin_amdgcn_mfma_f32_16x16x32_bf16(af, bf, acc[nt], 0,0,0);
    }
    __syncthreads();
    if (s<35){ commit(); __syncthreads(); }
  }
  #pragma unroll
  for (int nt=0;nt<8;nt++){
    int o = nt*16 + ln;
    float bias = dc_b[o];
    #pragma unroll
    for (int r=0;r<4;r++){
      int px = pbase + w*16 + q*4 + r;
      dc_t[((size_t)b*HW + px)*NC + o] = acc[nt][r] + bias;
    }
  }
}

// ---------------- K7: channel LayerNorm + sigmoid gate + multiply ----------------
__global__ __launch_bounds__(256) void epilogue(const float* __restrict__ dc_t,
    const float* __restrict__ dsc, const float* __restrict__ ln_g,
    const float* __restrict__ ln_b, float* __restrict__ out){
  __shared__ float T[64*129];
  __shared__ float Ps[4*64], Qs[4*64], Ms[64], Rs[64];
  int blk = blockIdx.x;                      // 576
  int b = rfl(blk/144); int pbase = rfl(blk - (blk/144)*144)*64;
  int t = threadIdx.x;
  #pragma unroll
  for (int i=0;i<8;i++){
    int idx = i*256 + t; int px = idx>>5, seg = idx&31;
    float4 v = *(const float4*)(dc_t + ((size_t)b*HW + pbase + px)*NC + seg*4);
    float* d = &T[px*129 + seg*4];
    d[0]=v.x; d[1]=v.y; d[2]=v.z; d[3]=v.w;
  }
  __syncthreads();
  int px = t&63, cg = t>>6;
  float s=0.f, ss=0.f;
  #pragma unroll
  for (int i=0;i<32;i++){ float v = T[px*129 + cg*32 + i]; s += v; ss = fmaf(v,v,ss); }
  Ps[cg*64+px] = s; Qs[cg*64+px] = ss;
  __syncthreads();
  if (t<64){
    float S = Ps[px]+Ps[64+px]+Ps[128+px]+Ps[192+px];
    float SS= Qs[px]+Qs[64+px]+Qs[128+px]+Qs[192+px];
    float m = S*(1.f/128.f);
    float var = SS*(1.f/128.f) - m*m;
    Ms[px] = m; Rs[px] = rsqrtf(var + 1e-5f);
  }
  __syncthreads();
  float m = Ms[px], rs = Rs[px];
  #pragma unroll 4
  for (int i=0;i<32;i++){
    int c = cg*32 + i;
    float ln = (T[px*129+c] - m)*rs*ln_g[c] + ln_b[c];
    float attn = 1.f/(1.f+__expf(-ln));
    size_t idx = (size_t)(b*NC+c)*HW + pbase + px;
    out[idx] = dsc[idx]*attn;
  }
}

extern "C" void kernel_launch(void* const* d_in, const int* in_sizes, int n_in,
                              void* d_out, int out_size, void* d_ws, size_t ws_size,
                              hipStream_t stream){
  const float* x    = (const float*)d_in[0];
  const float* dw_w = (const float*)d_in[1];
  const float* dw_b = (const float*)d_in[2];
  const float* pw_w = (const float*)d_in[3];
  const float* pw_b = (const float*)d_in[4];
  const float* off_w= (const float*)d_in[5];
  const float* off_b= (const float*)d_in[6];
  const float* dc_w = (const float*)d_in[7];
  const float* dc_b = (const float*)d_in[8];
  const float* ln_g = (const float*)d_in[9];
  const float* ln_b = (const float*)d_in[10];
  float* out = (float*)d_out;

  float* W    = (float*)d_ws;
  float*   bufA = W;                          // h1, then dsc (NCHW f32)
  float*   bufB = W + 4718592;                // h2, then dc_t (NHWC f32)
  u16*     dscT = (u16*)(W + 9437184);        // NHWC bf16 (4718592 u16)
  float*   po   = W + 11796480;               // 16 partial offset buffers
  float4*  wg   = (float4*)(W + 14450688);
  ushort4* ad   = (ushort4*)(W + 15777792);
  float*   st   = W + 16441344;
  u16*     wpwb = (u16*)(W + 16442368);       // 16384 u16
  float*   owt  = W + 16450560;
  u16*     wdcb = (u16*)(W + 16471296);       // 147456 u16
  // total: ~16.55M floats (~66 MB)

  prep_weights<<<576, 256, 0, stream>>>(pw_w, off_w, dc_w, wpwb, owt, wdcb);
  dw_conv     <<<18432, 256, 0, stream>>>(x, dw_w, dw_b, bufA);
  pw_mfma     <<<576, 256, 0, stream>>>(bufA, wpwb, pw_b, bufB);
  inorm_stats <<<512, 256, 0, stream>>>(bufB, st);
  make_dsc    <<<1152, 256, 0, stream>>>(bufB, st, bufA, dscT);
  off_conv    <<<576, 256, 0, stream>>>(bufA, owt, po);
  precomp     <<<1296, 256, 0, stream>>>(po, off_b, wg, ad);
  deform_mfma <<<576, 256, 0, stream>>>(dscT, wdcb, dc_b, wg, ad, bufB);
  epilogue    <<<576, 256, 0, stream>>>(bufB, bufA, ln_g, ln_b, out);
}

// Round 3
// 241.910 us; speedup vs baseline: 2.6701x; 1.3929x over previous
//
#include <hip/hip_runtime.h>
#include <math.h>

#define HW 9216
#define WD 96
#define NC 128

typedef unsigned short u16;
typedef __attribute__((ext_vector_type(8))) short short8;
typedef __attribute__((ext_vector_type(4))) float v4f;

__device__ __forceinline__ int rfl(int v){ return __builtin_amdgcn_readfirstlane(v); }
__device__ __forceinline__ float bu2f(u16 s){ return __uint_as_float(((unsigned)s)<<16); }
__device__ __forceinline__ u16 f2b(float f){ unsigned u = __float_as_uint(f);
  return (u16)((u + 0x7fffu + ((u>>16)&1u))>>16); }

// ---------------- K0: weight prep ----------------
// wpwb[o][c] = bf16(pw_w[o][c])
// wob[o][k*128+c] = bf16(off_w[o][c][k]) for o<18, else 0   (padded to 32 rows)
// wdcb[o][k*128+c] = bf16(dc_w[o][c][k])
__global__ __launch_bounds__(256) void prep_weights(const float* __restrict__ pw_w,
    const float* __restrict__ off_w, const float* __restrict__ dc_w,
    u16* __restrict__ wpwb, u16* __restrict__ wob, u16* __restrict__ wdcb){
  int t = blockIdx.x*256 + threadIdx.x;
  if (t < 16384) wpwb[t] = f2b(pw_w[t]);
  if (t < 36864){ int o = t/1152, r = t - o*1152; int k = r>>7, c = r&127;
                  wob[t] = (o<18) ? f2b(off_w[(o*128+c)*9+k]) : (u16)0; }
  if (t < 147456){ int o = t/1152, r = t - o*1152; int k = r>>7, c = r&127;
                   wdcb[t] = f2b(dc_w[(o*128+c)*9 + k]); }
}

// ---------------- K1: depthwise 3x3 + bias (NCHW fp32) ----------------
__global__ __launch_bounds__(256) void dw_conv(const float* __restrict__ x,
    const float* __restrict__ w, const float* __restrict__ bias, float* __restrict__ h1){
  int n = blockIdx.x*256 + threadIdx.x;          // 4718592 total
  int bc = rfl(n / HW);
  int p = n - bc*HW;
  int c = bc & 127;
  int yy = p / WD, xx = p - (p/WD)*WD;
  const float* xc = x + (size_t)bc*HW;
  float acc = bias[c];
  #pragma unroll
  for (int r=0;r<3;r++){
    int y2 = yy + r - 1;
    #pragma unroll
    for (int cc2=0;cc2<3;cc2++){
      int x2 = xx + cc2 - 1;
      if (y2>=0 && y2<96 && x2>=0 && x2<96)
        acc = fmaf(w[c*9 + r*3 + cc2], xc[y2*WD + x2], acc);
    }
  }
  h1[n] = acc;
}

// ---------------- K2: pointwise 1x1 via MFMA  (A=weights[o][c], B=act[c][px]) ----
__global__ __launch_bounds__(256) void pw_mfma(const float* __restrict__ h1,
    const u16* __restrict__ wpwb, const float* __restrict__ pw_b, float* __restrict__ h2){
  __shared__ short Aw[128*136];
  __shared__ short Bw[128*68];
  int blk = blockIdx.x; int row0 = blk*64;       // 576 blocks
  int b = rfl(row0/HW); int pbase = rfl(row0 - b*HW);
  int t = threadIdx.x;
  #pragma unroll
  for (int i=0;i<8;i++){                          // stage full W (128x128 bf16)
    int idx = i*256 + t; int o = idx>>4, seg = idx&15;
    *(short8*)&Aw[o*136 + seg*8] = *(const short8*)(wpwb + o*128 + seg*8);
  }
  #pragma unroll
  for (int i=0;i<8;i++){                          // stage act tile [128c][64px] fp32->bf16
    int idx = i*256 + t; int c = idx>>4, seg = idx&15;
    float4 v = *(const float4*)(h1 + (size_t)(b*NC+c)*HW + pbase + seg*4);
    ushort4 pk = make_ushort4(f2b(v.x), f2b(v.y), f2b(v.z), f2b(v.w));
    *(ushort4*)&Bw[c*68 + seg*4] = pk;
  }
  __syncthreads();
  int w = rfl(t>>6); int l = t&63; int q = l>>4; int ln = l&15;
  v4f acc[8];
  #pragma unroll
  for (int mt=0;mt<8;mt++) acc[mt] = (v4f){0.f,0.f,0.f,0.f};
  #pragma unroll
  for (int ks=0;ks<4;ks++){
    short8 bf;
    #pragma unroll
    for (int j=0;j<8;j++) bf[j] = Bw[(ks*32 + q*8 + j)*68 + w*16 + ln];
    #pragma unroll
    for (int mt=0;mt<8;mt++){
      short8 af = *(short8*)&Aw[(mt*16+ln)*136 + ks*32 + q*8];
      acc[mt] = __builtin_amdgcn_mfma_f32_16x16x32_bf16(af, bf, acc[mt], 0,0,0);
    }
  }
  int px = pbase + w*16 + ln;
  #pragma unroll
  for (int mt=0;mt<8;mt++){
    #pragma unroll
    for (int r=0;r<4;r++){
      int o = mt*16 + q*4 + r;
      h2[(size_t)(b*NC+o)*HW + px] = acc[mt][r] + pw_b[o];
    }
  }
}

// ---------------- K3: InstanceNorm stats ----------------
__global__ __launch_bounds__(256) void inorm_stats(const float* __restrict__ h2, float* __restrict__ st){
  int bc = blockIdx.x;                       // 512
  const float* src = h2 + (size_t)bc*HW;
  float s=0.f, ss=0.f;
  for (int i=threadIdx.x; i<HW; i+=256){ float v=src[i]; s+=v; ss=fmaf(v,v,ss); }
  #pragma unroll
  for (int off=32; off; off>>=1){ s += __shfl_down(s,off); ss += __shfl_down(ss,off); }
  __shared__ float rsm[2][4];
  int wave = threadIdx.x>>6, lane = threadIdx.x&63;
  if (lane==0){ rsm[0][wave]=s; rsm[1][wave]=ss; }
  __syncthreads();
  if (threadIdx.x==0){
    float S = rsm[0][0]+rsm[0][1]+rsm[0][2]+rsm[0][3];
    float SS= rsm[1][0]+rsm[1][1]+rsm[1][2]+rsm[1][3];
    float mu = S * (1.f/9216.f);
    float var = SS * (1.f/9216.f) - mu*mu;
    st[bc*2]   = mu;
    st[bc*2+1] = rsqrtf(var + 1e-5f);
  }
}

// ---------------- K4: dsc (NCHW fp32) + dscT/dscL (NHWC bf16 hi/lo) ----------------
__global__ __launch_bounds__(256) void make_dsc(const float* __restrict__ h2,
    const float* __restrict__ st, float* __restrict__ dsc,
    u16* __restrict__ dscT, u16* __restrict__ dscL){
  int blk = blockIdx.x;                      // 1152 = 4b * 2ch * 144pt
  int pt = blk % 144; int r = blk/144; int ch = r & 1; int b = r >> 1;
  int c0 = ch*64, pbase = pt*64;
  __shared__ float tile[64][65];
  int tr = threadIdx.x >> 2;                 // 0..63
  int g  = threadIdx.x & 3;                  // 0..3
  int c  = c0 + tr;
  float mu = st[(b*128+c)*2];
  float rs = st[(b*128+c)*2+1];
  const float* src = h2 + (size_t)(b*128+c)*HW + pbase + g*16;
  float* d = dsc + (size_t)(b*128+c)*HW + pbase + g*16;
  #pragma unroll
  for (int i=0;i<4;i++){
    float4 v = *(const float4*)(src + i*4);
    v.x=(v.x-mu)*rs; v.y=(v.y-mu)*rs; v.z=(v.z-mu)*rs; v.w=(v.w-mu)*rs;
    *(float4*)(d + i*4) = v;
    tile[tr][g*16+i*4+0]=v.x; tile[tr][g*16+i*4+1]=v.y;
    tile[tr][g*16+i*4+2]=v.z; tile[tr][g*16+i*4+3]=v.w;
  }
  __syncthreads();
  int pr = tr;
  u16* dt = dscT + ((size_t)b*HW + pbase + pr)*NC + c0 + g*16;
  u16* dl = dscL + ((size_t)b*HW + pbase + pr)*NC + c0 + g*16;
  #pragma unroll
  for (int i=0;i<4;i++){
    float v0 = tile[g*16+i*4+0][pr], v1 = tile[g*16+i*4+1][pr];
    float v2 = tile[g*16+i*4+2][pr], v3 = tile[g*16+i*4+3][pr];
    ushort4 hi = make_ushort4(f2b(v0), f2b(v1), f2b(v2), f2b(v3));
    ushort4 lo = make_ushort4(f2b(v0-bu2f(hi.x)), f2b(v1-bu2f(hi.y)),
                              f2b(v2-bu2f(hi.z)), f2b(v3-bu2f(hi.w)));
    *(ushort4*)(dt + i*4) = hi;
    *(ushort4*)(dl + i*4) = lo;
  }
}

// ---------------- K5: offset conv via MFMA (im2col, hi/lo split) + fused bilinear precomp ----
// offsets[px][o<18] = sum_K (a_hi + a_lo)[px][K] * w[o][K],  K = tap*128 + c
__global__ __launch_bounds__(256) void off_mfma(const u16* __restrict__ dscT,
    const u16* __restrict__ dscL, const u16* __restrict__ wob,
    const float* __restrict__ off_b, float4* __restrict__ wg, ushort4* __restrict__ ad){
  __shared__ short As[2][64*40];             // hi/lo A tiles (64 px x 32 K), pad 40
  __shared__ short Bs[32*40];                // W tile (32 o x 32 K)
  __shared__ float Po[18*64];                // offsets [o][px]
  int blk = blockIdx.x; int row0 = blk*64;   // 576 blocks
  int b = rfl(row0/HW); int pbase = rfl(row0 - b*HW);
  int t = threadIdx.x;
  int apx = t>>2, aseg = t&3;                // A staging: pixel, 8-ch group
  int bo = t>>3, bseg = t&7;                 // B staging: o row, 4-k group
  int w = rfl(t>>6); int l = t&63; int q = l>>4; int ln = l&15;
  int P = pbase + apx;
  int py = P/96, px_ = P - 96*(P/96);
  const u16* hib = dscT + (size_t)b*HW*NC;
  const u16* lob = dscL + (size_t)b*HW*NC;
  uint4 rh, rl; ushort4 wb;
  auto prefetch = [&](int s){
    int k = s>>2, cseg = s&3;
    int y2 = py + k/3 - 1, x2 = px_ + k%3 - 1;
    bool valid = ((unsigned)y2 < 96u) && ((unsigned)x2 < 96u);
    int off = ((y2*96 + x2)*NC) + cseg*32 + aseg*8;
    rh = valid ? *(const uint4*)(hib + off) : (uint4){0,0,0,0};
    rl = valid ? *(const uint4*)(lob + off) : (uint4){0,0,0,0};
    wb = *(const ushort4*)(wob + bo*1152 + k*128 + cseg*32 + bseg*4);
  };
  auto commit = [&](){
    *(short8*)&As[0][apx*40 + aseg*8] = *(short8*)&rh;
    *(short8*)&As[1][apx*40 + aseg*8] = *(short8*)&rl;
    *(ushort4*)&Bs[bo*40 + bseg*4] = wb;
  };
  v4f acc[2];
  acc[0] = (v4f){0.f,0.f,0.f,0.f}; acc[1] = (v4f){0.f,0.f,0.f,0.f};
  prefetch(0); commit();
  __syncthreads();
  #pragma unroll 1
  for (int s=0;s<36;s++){
    if (s<35) prefetch(s+1);
    short8 ah = *(short8*)&As[0][(w*16+ln)*40 + q*8];
    short8 al = *(short8*)&As[1][(w*16+ln)*40 + q*8];
    short8 b0 = *(short8*)&Bs[ln*40 + q*8];
    short8 b1 = *(short8*)&Bs[(16+ln)*40 + q*8];
    acc[0] = __builtin_amdgcn_mfma_f32_16x16x32_bf16(ah, b0, acc[0], 0,0,0);
    acc[1] = __builtin_amdgcn_mfma_f32_16x16x32_bf16(ah, b1, acc[1], 0,0,0);
    acc[0] = __builtin_amdgcn_mfma_f32_16x16x32_bf16(al, b0, acc[0], 0,0,0);
    acc[1] = __builtin_amdgcn_mfma_f32_16x16x32_bf16(al, b1, acc[1], 0,0,0);
    __syncthreads();
    if (s<35){ commit(); __syncthreads(); }
  }
  #pragma unroll
  for (int nt=0;nt<2;nt++){
    int o = nt*16 + ln;
    if (o < 18){
      float ob = off_b[o];
      #pragma unroll
      for (int r=0;r<4;r++) Po[o*64 + w*16 + q*4 + r] = acc[nt][r] + ob;
    }
  }
  __syncthreads();
  #pragma unroll
  for (int i=0;i<3;i++){
    int idx = i*256 + t;
    if (idx < 576){
      int pxl = idx & 63, k = idx >> 6;
      int Pp = pbase + pxl;
      float dy = Po[(2*k)*64 + pxl], dx = Po[(2*k+1)*64 + pxl];
      float ys = (float)(Pp/96 + k/3 - 1) + dy;
      float xs = (float)(Pp%96 + k%3 - 1) + dx;
      float fy0 = floorf(ys), fx0 = floorf(xs);
      float wy = ys - fy0, wx = xs - fx0;
      int y0 = (int)fy0, x0 = (int)fx0;
      int y1 = y0+1, x1 = x0+1;
      float vy0 = (y0>=0 && y0<=95) ? 1.f : 0.f;
      float vy1 = (y1>=0 && y1<=95) ? 1.f : 0.f;
      float vx0 = (x0>=0 && x0<=95) ? 1.f : 0.f;
      float vx1 = (x1>=0 && x1<=95) ? 1.f : 0.f;
      int y0c=min(max(y0,0),95), y1c=min(max(y1,0),95);
      int x0c=min(max(x0,0),95), x1c=min(max(x1,0),95);
      float4 w4;
      w4.x = (1.f-wy)*(1.f-wx)*vy0*vx0;
      w4.y = (1.f-wy)*wx*vy0*vx1;
      w4.z = wy*(1.f-wx)*vy1*vx0;
      w4.w = wy*wx*vy1*vx1;
      int gi = (b*9 + k)*HW + pbase + pxl;
      wg[gi] = w4;
      ad[gi] = make_ushort4((u16)(y0c*WD+x0c), (u16)(y0c*WD+x1c),
                            (u16)(y1c*WD+x0c), (u16)(y1c*WD+x1c));
    }
  }
}

// ---------------- K6: fused deform conv: gather->LDS + MFMA GEMM ----------------
__global__ __launch_bounds__(256) void deform_mfma(const u16* __restrict__ dscT,
    const u16* __restrict__ wdcb, const float* __restrict__ dc_b,
    const float4* __restrict__ wg, const ushort4* __restrict__ ad,
    float* __restrict__ dc_t){
  __shared__ short As[64*40];
  __shared__ short Bs[128*40];
  int blk = blockIdx.x; int row0 = blk*64;   // 576 blocks
  int b = rfl(row0/HW); int pbase = rfl(row0 - b*HW);
  int t = threadIdx.x;
  int am = t>>2, aseg = t&3;
  int o0 = t>>2, bseg = t&3;
  int w = rfl(t>>6); int l = t&63; int q = l>>4; int ln = l&15;
  const u16* db0 = dscT + (size_t)b*HW*NC;
  float4 wv; ushort4 av; uint4 r0,r1,r2,r3, wb0, wb1;
  auto prefetch = [&](int s){
    int k = s>>2; int cs = ((s&3)<<5) + aseg*8;
    int wgi = (b*9 + k)*HW + pbase + am;
    wv = wg[wgi]; av = ad[wgi];
    const u16* db = db0 + cs;
    r0 = *(const uint4*)(db + (int)av.x*NC);
    r1 = *(const uint4*)(db + (int)av.y*NC);
    r2 = *(const uint4*)(db + (int)av.z*NC);
    r3 = *(const uint4*)(db + (int)av.w*NC);
    const u16* wp = wdcb + s*32 + bseg*8;
    wb0 = *(const uint4*)(wp + o0*1152);
    wb1 = *(const uint4*)(wp + (o0+64)*1152);
  };
  auto commit = [&](){
    const u16* pa=(const u16*)&r0; const u16* pb=(const u16*)&r1;
    const u16* pc=(const u16*)&r2; const u16* pd=(const u16*)&r3;
    short8 sv;
    #pragma unroll
    for (int j=0;j<8;j++){
      float f = wv.x*bu2f(pa[j]) + wv.y*bu2f(pb[j]) + wv.z*bu2f(pc[j]) + wv.w*bu2f(pd[j]);
      sv[j] = (short)f2b(f);
    }
    *(short8*)&As[am*40 + aseg*8] = sv;
    *(short8*)&Bs[o0*40 + bseg*8] = *(short8*)&wb0;
    *(short8*)&Bs[(o0+64)*40 + bseg*8] = *(short8*)&wb1;
  };
  v4f acc[8];
  #pragma unroll
  for (int nt=0;nt<8;nt++) acc[nt] = (v4f){0.f,0.f,0.f,0.f};
  prefetch(0); commit();
  __syncthreads();
  #pragma unroll 1
  for (int s=0;s<36;s++){
    if (s<35) prefetch(s+1);
    short8 af = *(short8*)&As[(w*16+ln)*40 + q*8];
    #pragma unroll
    for (int nt=0;nt<8;nt++){
      short8 bf = *(short8*)&Bs[(nt*16+ln)*40 + q*8];
      acc[nt] = __builtin_amdgcn_mfma_f32_16x16x32_bf16(af, bf, acc[nt], 0,0,0);
    }
    __syncthreads();
    if (s<35){ commit(); __syncthreads(); }
  }
  #pragma unroll
  for (int nt=0;nt<8;nt++){
    int o = nt*16 + ln;
    float bias = dc_b[o];
    #pragma unroll
    for (int r=0;r<4;r++){
      int px = pbase + w*16 + q*4 + r;
      dc_t[((size_t)b*HW + px)*NC + o] = acc[nt][r] + bias;
    }
  }
}

// ---------------- K7: channel LayerNorm + sigmoid gate + multiply ----------------
__global__ __launch_bounds__(256) void epilogue(const float* __restrict__ dc_t,
    const float* __restrict__ dsc, const float* __restrict__ ln_g,
    const float* __restrict__ ln_b, float* __restrict__ out){
  __shared__ float T[64*129];
  __shared__ float Ps[4*64], Qs[4*64], Ms[64], Rs[64];
  int blk = blockIdx.x;                      // 576
  int b = rfl(blk/144); int pbase = rfl(blk - (blk/144)*144)*64;
  int t = threadIdx.x;
  #pragma unroll
  for (int i=0;i<8;i++){
    int idx = i*256 + t; int px = idx>>5, seg = idx&31;
    float4 v = *(const float4*)(dc_t + ((size_t)b*HW + pbase + px)*NC + seg*4);
    float* d = &T[px*129 + seg*4];
    d[0]=v.x; d[1]=v.y; d[2]=v.z; d[3]=v.w;
  }
  __syncthreads();
  int px = t&63, cg = t>>6;
  float s=0.f, ss=0.f;
  #pragma unroll
  for (int i=0;i<32;i++){ float v = T[px*129 + cg*32 + i]; s += v; ss = fmaf(v,v,ss); }
  Ps[cg*64+px] = s; Qs[cg*64+px] = ss;
  __syncthreads();
  if (t<64){
    float S = Ps[px]+Ps[64+px]+Ps[128+px]+Ps[192+px];
    float SS= Qs[px]+Qs[64+px]+Qs[128+px]+Qs[192+px];
    float m = S*(1.f/128.f);
    float var = SS*(1.f/128.f) - m*m;
    Ms[px] = m; Rs[px] = rsqrtf(var + 1e-5f);
  }
  __syncthreads();
  float m = Ms[px], rs = Rs[px];
  #pragma unroll 4
  for (int i=0;i<32;i++){
    int c = cg*32 + i;
    float ln = (T[px*129+c] - m)*rs*ln_g[c] + ln_b[c];
    float attn = 1.f/(1.f+__expf(-ln));
    size_t idx = (size_t)(b*NC+c)*HW + pbase + px;
    out[idx] = dsc[idx]*attn;
  }
}

extern "C" void kernel_launch(void* const* d_in, const int* in_sizes, int n_in,
                              void* d_out, int out_size, void* d_ws, size_t ws_size,
                              hipStream_t stream){
  const float* x    = (const float*)d_in[0];
  const float* dw_w = (const float*)d_in[1];
  const float* dw_b = (const float*)d_in[2];
  const float* pw_w = (const float*)d_in[3];
  const float* pw_b = (const float*)d_in[4];
  const float* off_w= (const float*)d_in[5];
  const float* off_b= (const float*)d_in[6];
  const float* dc_w = (const float*)d_in[7];
  const float* dc_b = (const float*)d_in[8];
  const float* ln_g = (const float*)d_in[9];
  const float* ln_b = (const float*)d_in[10];
  float* out = (float*)d_out;

  float* W    = (float*)d_ws;
  float*   bufA = W;                          // h1, then dsc (NCHW f32)
  float*   bufB = W + 4718592;                // h2, then dc_t (NHWC f32)
  u16*     dscT = (u16*)(W + 9437184);        // NHWC bf16 hi (4718592 u16)
  u16*     dscL = (u16*)(W + 11796480);       // NHWC bf16 lo residual
  float4*  wg   = (float4*)(W + 14155776);    // 331776 float4
  ushort4* ad   = (ushort4*)(W + 15482880);   // 331776 ushort4
  float*   st   = W + 16146432;
  u16*     wpwb = (u16*)(W + 16147456);       // 16384 u16
  u16*     wob  = (u16*)(W + 16155648);       // 36864 u16
  u16*     wdcb = (u16*)(W + 16174080);       // 147456 u16
  // end ~16.25M floats (~65 MB)

  prep_weights<<<576, 256, 0, stream>>>(pw_w, off_w, dc_w, wpwb, wob, wdcb);
  dw_conv     <<<18432, 256, 0, stream>>>(x, dw_w, dw_b, bufA);
  pw_mfma     <<<576, 256, 0, stream>>>(bufA, wpwb, pw_b, bufB);
  inorm_stats <<<512, 256, 0, stream>>>(bufB, st);
  make_dsc    <<<1152, 256, 0, stream>>>(bufB, st, bufA, dscT, dscL);
  off_mfma    <<<576, 256, 0, stream>>>(dscT, dscL, wob, off_b, wg, ad);
  deform_mfma <<<576, 256, 0, stream>>>(dscT, wdcb, dc_b, wg, ad, bufB);
  epilogue    <<<576, 256, 0, stream>>>(bufB, bufA, ln_g, ln_b, out);
}